// Round 5
// baseline (91.271 us; speedup 1.0000x reference)
//
#include <hip/hip_runtime.h>

// out[b][j] = table_bits[idx(b)][j]; idx(b) = MSB-first pack of (idx_bits[b][k] > 0).
// Streaming floor: 6 MiB idx read + 64 MiB out write ~= 11.5 us at the 6.1 TB/s
// fill pace. R5: two-kernel, barrier-free design.
//   kernel0: table (16 KB) -> 64 x uint64 bitmasks in d_ws (512 B), via __ballot.
//   kernel1: one float4 per thread, no LDS, no barrier, pure TLP streaming.
// NT stores regressed in R4 (80.2 -> 87.5 us) -> plain stores here.

typedef float nfloat4 __attribute__((ext_vector_type(4)));

__global__ __launch_bounds__(256) void
make_masks_kernel(const float* __restrict__ table,          // [64][64] float32
                  unsigned long long* __restrict__ masks) { // [64]
    const int wave = threadIdx.x >> 6;
    const int lane = threadIdx.x & 63;
    // Wave w compresses rows 16w..16w+15; lane j reads bit j (coalesced dword).
    #pragma unroll
    for (int i = 0; i < 16; ++i) {
        const int row = wave * 16 + i;
        const float f = table[row * 64 + lane];
        const unsigned long long m = __ballot(f > 0.5f);
        if (lane == 0) masks[row] = m;
    }
}

__global__ __launch_bounds__(256) void
spike_lut_kernel(const unsigned long long* __restrict__ masks, // [64]
                 const int* __restrict__ idx_bits,             // [batch][6]
                 nfloat4* __restrict__ out4,                   // [batch][16]
                 long n4) {                                    // batch*16
    const long g = (long)blockIdx.x * 256 + threadIdx.x;
    if (g >= n4) return;

    const long b = g >> 4;        // batch row (16 consecutive threads share it)
    const int  q = (int)(g & 15); // float4 column

    // 6 dword loads; addresses duplicate across 16 lanes -> L1-merged broadcast.
    const int* p = idx_bits + b * 6;
    int idx = 0;
    #pragma unroll
    for (int k = 0; k < 6; ++k)
        idx = (idx << 1) | (p[k] > 0 ? 1 : 0);   // k=0 is MSB (weight 32)

    // 8 B mask load from the 512 B table (L1-hot after first touch).
    const unsigned int r = (unsigned int)(masks[idx] >> (q * 4));

    nfloat4 v;
    v.x = (r & 1u) ? 1.0f : 0.0f;
    v.y = (r & 2u) ? 1.0f : 0.0f;
    v.z = (r & 4u) ? 1.0f : 0.0f;
    v.w = (r & 8u) ? 1.0f : 0.0f;
    out4[g] = v;   // consecutive lanes at consecutive 16 B -> global_store_dwordx4
}

extern "C" void kernel_launch(void* const* d_in, const int* in_sizes, int n_in,
                              void* d_out, int out_size, void* d_ws, size_t ws_size,
                              hipStream_t stream) {
    const float* table    = (const float*)d_in[0];   // [64,64] float32
    const int*   idx_bits = (const int*)d_in[1];     // [batch,6] int32
    nfloat4*     out4     = (nfloat4*)d_out;
    unsigned long long* masks = (unsigned long long*)d_ws;   // 512 B scratch

    const int  batch = in_sizes[1] / 6;
    const long n4    = (long)batch * 16;
    const int  blocks = (int)((n4 + 255) / 256);

    make_masks_kernel<<<1, 256, 0, stream>>>(table, masks);
    spike_lut_kernel<<<blocks, 256, 0, stream>>>(masks, idx_bits, out4, n4);
}

// Round 6
// 84.074 us; speedup vs baseline: 1.0856x; 1.0856x over previous
//
#include <hip/hip_runtime.h>

// out[b][j] = table_bits[idx(b)][j]; idx(b) = MSB-first pack of (idx_bits[b][k] > 0).
// R6 = R4 ablation: identical structure (ballot-compressed table -> 64 x u64 masks
// in LDS, per-thread direct idx loads, single barrier) but PLAIN dwordx4 stores —
// isolates the nontemporal-store cost (R4: 87.5 us vs R2: 80.2 us).
// Harness floor ~57 us (ws+out re-poison); kernel share target ~23 us.

#define ROWS 256   // batch rows per block: 256 rows x 64 floats = 64 KB out/block

typedef float nfloat4 __attribute__((ext_vector_type(4)));

__global__ __launch_bounds__(256) void
spike_lut_kernel(const float* __restrict__ table,      // [64 rows][64 bits] float32
                 const int* __restrict__ idx_bits,     // [batch][6] int32
                 nfloat4* __restrict__ out4,           // [batch][16] float4
                 int batch) {
    __shared__ unsigned long long s_mask[64];   // bit j of s_mask[r] = table[r][j] > 0
    __shared__ int s_idx[ROWS];

    const int  tid  = threadIdx.x;
    const int  wave = tid >> 6;
    const int  lane = tid & 63;
    const long b0   = (long)blockIdx.x * ROWS;
    const bool full = (b0 + ROWS) <= batch;     // uniform per block

    // Phase A: compress table rows to 64-bit masks. Wave w handles rows 16w..16w+15;
    // lane j reads table[row][j] (coalesced dword), one __ballot per row.
    #pragma unroll
    for (int i = 0; i < 16; ++i) {
        const int row = wave * 16 + i;
        const float f = table[row * 64 + lane];
        const unsigned long long m = __ballot(f > 0.5f);
        if (lane == 0) s_mask[row] = m;
    }

    // Phase B: each thread packs its own row's 6-bit index (3x dwordx2/thread;
    // every byte of the 24B stride is consumed across the wave).
    {
        int idx = 0;
        const long b = b0 + tid;
        if (b < (long)batch) {
            const int* p = idx_bits + b * 6;
            #pragma unroll
            for (int k = 0; k < 6; ++k)
                idx = (idx << 1) | (p[k] > 0 ? 1 : 0);   // k=0 is MSB (weight 32)
        }
        s_idx[tid] = idx;
    }
    __syncthreads();   // the only barrier

    // Phase C: 16 lanes share one row -> both LDS reads are broadcasts; each lane
    // expands its fixed nibble (q = tid&15) of the row mask to a float4 and
    // streams it out (plain dwordx4, consecutive lanes -> consecutive 16B).
    if (full) {
        #pragma unroll
        for (int it = 0; it < 16; ++it) {
            const int g  = it * 256 + tid;
            const int bl = g >> 4;
            const int q  = g & 15;
            const unsigned int r = (unsigned int)(s_mask[s_idx[bl]] >> (q * 4));
            nfloat4 v;
            v.x = (r & 1u) ? 1.0f : 0.0f;
            v.y = (r & 2u) ? 1.0f : 0.0f;
            v.z = (r & 4u) ? 1.0f : 0.0f;
            v.w = (r & 8u) ? 1.0f : 0.0f;
            out4[(b0 + bl) * 16 + q] = v;
        }
    } else {
        #pragma unroll
        for (int it = 0; it < 16; ++it) {
            const int g  = it * 256 + tid;
            const int bl = g >> 4;
            const int q  = g & 15;
            if (b0 + bl < batch) {
                const unsigned int r = (unsigned int)(s_mask[s_idx[bl]] >> (q * 4));
                nfloat4 v;
                v.x = (r & 1u) ? 1.0f : 0.0f;
                v.y = (r & 2u) ? 1.0f : 0.0f;
                v.z = (r & 4u) ? 1.0f : 0.0f;
                v.w = (r & 8u) ? 1.0f : 0.0f;
                out4[(b0 + bl) * 16 + q] = v;
            }
        }
    }
}

extern "C" void kernel_launch(void* const* d_in, const int* in_sizes, int n_in,
                              void* d_out, int out_size, void* d_ws, size_t ws_size,
                              hipStream_t stream) {
    const float* table    = (const float*)d_in[0];   // [64,64] float32
    const int*   idx_bits = (const int*)d_in[1];     // [batch,6] int32
    nfloat4*     out4     = (nfloat4*)d_out;

    const int batch  = in_sizes[1] / 6;
    const int blocks = (batch + ROWS - 1) / ROWS;

    spike_lut_kernel<<<blocks, 256, 0, stream>>>(table, idx_bits, out4, batch);
}

// Round 7
// 79.641 us; speedup vs baseline: 1.1460x; 1.0557x over previous
//
#include <hip/hip_runtime.h>

// out[b][j] = table_bits[idx(b)][j]; idx(b) = MSB-first pack of (idx_bits[b][k] > 0).
// R7 = R2 (best: 80.2 us) + global_load_lds staging (async global->LDS, no VGPR
// round-trip). Ledger: R1 80.7 / R2 80.2 / R4(NT) 87.5 / R5(2-kernel) 91.3 /
// R6(ballot) 84.1 -> staged-LDS-table + coalesced idx staging + plain dwordx4
// stores is the winning structure; this round only shaves the prologue.
// Window floor ~= 57 us harness re-poison + ~11.5 us kernel streaming minimum.

#define ROWS 256   // batch rows per block: 256 rows x 64 floats = 64 KB out/block

typedef float nfloat4 __attribute__((ext_vector_type(4)));
#define GLOBAL_AS __attribute__((address_space(1)))
#define LDS_AS    __attribute__((address_space(3)))

__global__ __launch_bounds__(256) void
spike_lut_kernel(const float* __restrict__ table,      // [64 rows][64 bits] float32
                 const int* __restrict__ idx_bits,     // [batch][6] int32
                 nfloat4* __restrict__ out4,           // [batch][16] float4
                 int batch) {
    __shared__ nfloat4 s_table[64 * 16];   // 16 KB full table
    __shared__ int     s_raw[ROWS * 6];    // 6 KB staged idx_bits
    __shared__ int     s_idx[ROWS];        // 1 KB packed indices

    const int  tid  = threadIdx.x;
    const int  wv   = tid >> 6;            // wave id (0..3)
    const int  ln   = tid & 63;            // lane id
    const long b0   = (long)blockIdx.x * ROWS;
    const bool full = (b0 + ROWS) <= batch;   // uniform per block

    const nfloat4* t4  = (const nfloat4*)table;
    const int*     src = idx_bits + b0 * 6;

    if (full) {
        // Async global->LDS staging: LDS dest = wave-uniform base + lane*size.
        // Table: 4 x (64 lanes x 16 B) per wave slice; idx: 6 x (64 lanes x 4 B).
        #pragma unroll
        for (int r = 0; r < 4; ++r) {
            const int e = r * 256 + wv * 64;   // element base for this wave
            __builtin_amdgcn_global_load_lds(
                (const GLOBAL_AS void*)(t4 + e + ln),
                (LDS_AS void*)&s_table[e], 16, 0, 0);
        }
        #pragma unroll
        for (int r = 0; r < 6; ++r) {
            const int e = r * 256 + wv * 64;
            __builtin_amdgcn_global_load_lds(
                (const GLOBAL_AS void*)(src + e + ln),
                (LDS_AS void*)&s_raw[e], 4, 0, 0);
        }
    } else {
        // Tail block (not hit at batch=262144): plain guarded staging.
        #pragma unroll
        for (int r = 0; r < 4; ++r)
            s_table[r * 256 + tid] = t4[r * 256 + tid];
        const long lim = ((long)batch - b0) * 6;
        #pragma unroll
        for (int r = 0; r < 6; ++r) {
            const int g = r * 256 + tid;
            s_raw[g] = (g < lim) ? src[g] : 0;
        }
    }
    __syncthreads();   // drains vmcnt (incl. global_load_lds) before LDS reads

    // Each thread packs its row's 6-bit index from LDS (one-time, tiny).
    {
        const int* p = &s_raw[tid * 6];
        int idx = 0;
        #pragma unroll
        for (int k = 0; k < 6; ++k)
            idx = (idx << 1) | (p[k] > 0 ? 1 : 0);   // k=0 is MSB (weight 32)
        s_idx[tid] = idx;
    }
    __syncthreads();

    // Emit 256 rows x 16 float4 = 4096 float4/block; consecutive lanes hit
    // consecutive 16 B addresses -> 1 KB/wave global_store_dwordx4, fill-like.
    if (full) {
        #pragma unroll
        for (int it = 0; it < 16; ++it) {
            const int g  = it * 256 + tid;
            const int bl = g >> 4;
            const int q  = g & 15;
            out4[(b0 + bl) * 16 + q] = s_table[s_idx[bl] * 16 + q];
        }
    } else {
        #pragma unroll
        for (int it = 0; it < 16; ++it) {
            const int g  = it * 256 + tid;
            const int bl = g >> 4;
            const int q  = g & 15;
            if (b0 + bl < batch)
                out4[(b0 + bl) * 16 + q] = s_table[s_idx[bl] * 16 + q];
        }
    }
}

extern "C" void kernel_launch(void* const* d_in, const int* in_sizes, int n_in,
                              void* d_out, int out_size, void* d_ws, size_t ws_size,
                              hipStream_t stream) {
    const float* table    = (const float*)d_in[0];   // [64,64] float32
    const int*   idx_bits = (const int*)d_in[1];     // [batch,6] int32
    nfloat4*     out4     = (nfloat4*)d_out;

    const int batch  = in_sizes[1] / 6;
    const int blocks = (batch + ROWS - 1) / ROWS;

    spike_lut_kernel<<<blocks, 256, 0, stream>>>(table, idx_bits, out4, batch);
}